// Round 3
// baseline (970.640 us; speedup 1.0000x reference)
//
#include <hip/hip_runtime.h>

#define NROWS 65536
#define COVAR_Z 256

typedef unsigned short u16;
typedef short bf16x8 __attribute__((ext_vector_type(8)));    // 8 bf16 in 4 VGPRs (MFMA operand)
typedef u16 u16x8 __attribute__((ext_vector_type(8)));
typedef float f32x4 __attribute__((ext_vector_type(4)));

__device__ __forceinline__ u16 f2bf(float f) {
  unsigned int u = __builtin_bit_cast(unsigned int, f);
  u += 0x7FFFu + ((u >> 16) & 1u);   // round-to-nearest-even
  return (u16)(u >> 16);
}
__device__ __forceinline__ float bf2f(u16 s) {
  return __builtin_bit_cast(float, (unsigned int)s << 16);
}
__device__ __forceinline__ float sigd(u16 s) {    // h -> h*(1-h), f32 exact from bf16 h
  const float p = bf2f(s);
  return p * (1.0f - p);
}

// ---------------------------------------------------------------------------
// Weight prep: bf16 + transpose -> Wt[Nc][K] so B staging is k-contiguous.
// ---------------------------------------------------------------------------
__global__ void prep_weights(const float* __restrict__ eW0, const float* __restrict__ eW1,
                             const float* __restrict__ dW1, const float* __restrict__ dW2,
                             u16* __restrict__ eW0t, u16* __restrict__ eW1t,
                             u16* __restrict__ dW1t, u16* __restrict__ dW2t) {
  const int idx = blockIdx.x * 256 + threadIdx.x;
  if (idx < 131072) {                       // eW0 [512][256] -> eW0t[256][512]
    const int n = idx >> 9, k = idx & 511;
    eW0t[idx] = f2bf(eW0[k * 256 + n]);
  } else if (idx < 163840) {                // eW1 [256][128] -> eW1t[128][256]
    const int j = idx - 131072, n = j >> 8, k = j & 255;
    eW1t[j] = f2bf(eW1[k * 128 + n]);
  } else if (idx < 196608) {                // dW1 [128][256] -> dW1t[256][128]
    const int j = idx - 163840, n = j >> 7, k = j & 127;
    dW1t[j] = f2bf(dW1[k * 256 + n]);
  } else {                                  // dW2 [256][512] -> dW2t[512][256]
    const int j = idx - 196608, n = j >> 8, k = j & 255;
    dW2t[j] = f2bf(dW2[k * 512 + n]);
  }
}

// ---------------------------------------------------------------------------
// MFMA GEMM: C[M,Nc] = act(A[M,K] @ W[K,Nc] + bias).
// XCD chunked swizzle: work id -> contiguous chunk per XCD so n-split blocks
// sharing the same A row-stripe are L2-co-resident (x read 1x HBM, not 2-4x).
// ---------------------------------------------------------------------------
template <int ACT, int A_F32>
__global__ __launch_bounds__(256, 2) void gemm_mfma(const void* __restrict__ Av,
                                                    const u16* __restrict__ Wt,
                                                    const float* __restrict__ bias,
                                                    void* __restrict__ Cv, int K, int Nc) {
  __shared__ u16 As[128 * 32];
  __shared__ u16 Bs[128 * 32];
  const int tid = threadIdx.x;
  const int lane = tid & 63;
  const int wave = tid >> 6;

  // chunked XCD swizzle (gridDim.x is a power of two: 1/2/4; nwg % 8 == 0)
  const int gx = gridDim.x;
  const int nwg = gx * gridDim.y;
  int id = blockIdx.y * gx + blockIdx.x;
  id = (id & 7) * (nwg >> 3) + (id >> 3);
  const int lgx = __builtin_ctz(gx);
  const int n0 = (id & (gx - 1)) * 128;
  const int m0 = (id >> lgx) * 128;

  const int wm = (wave & 1) * 64;
  const int wn = (wave >> 1) * 64;
  const int q = lane >> 4;       // k-group 0..3
  const int mr = lane & 15;

  f32x4 acc[4][4] = {};

  for (int k0 = 0; k0 < K; k0 += 32) {
    // ---- stage A tile [128 rows][32 k] ----
    if (A_F32) {
      const float* A = (const float*)Av;
#pragma unroll
      for (int i = 0; i < 2; ++i) {
        const int c = tid + i * 256;           // 16B chunk id
        const int r = c >> 2, p = c & 3;
        const int g = (p - (r >> 1)) & 3;      // swizzled global k-chunk
        const float* src = A + (size_t)(m0 + r) * K + k0 + g * 8;
        const float4 v0 = *(const float4*)src;
        const float4 v1 = *(const float4*)(src + 4);
        u16x8 w;
        w[0] = f2bf(v0.x); w[1] = f2bf(v0.y); w[2] = f2bf(v0.z); w[3] = f2bf(v0.w);
        w[4] = f2bf(v1.x); w[5] = f2bf(v1.y); w[6] = f2bf(v1.z); w[7] = f2bf(v1.w);
        *(u16x8*)&As[c * 8] = w;
      }
    } else {
      const u16* A = (const u16*)Av;
#pragma unroll
      for (int i = 0; i < 2; ++i) {
        const int c = tid + i * 256;
        const int r = c >> 2, p = c & 3;
        const int g = (p - (r >> 1)) & 3;
        __builtin_amdgcn_global_load_lds(
            (const __attribute__((address_space(1))) void*)(A + (size_t)(m0 + r) * K + k0 + g * 8),
            (__attribute__((address_space(3))) void*)&As[(i * 256 + wave * 64) * 8], 16, 0, 0);
      }
    }
    // ---- stage B tile: Wt rows n0..n0+127, k chunk ----
    {
#pragma unroll
      for (int i = 0; i < 2; ++i) {
        const int c = tid + i * 256;
        const int r = c >> 2, p = c & 3;
        const int g = (p - (r >> 1)) & 3;
        __builtin_amdgcn_global_load_lds(
            (const __attribute__((address_space(1))) void*)(Wt + (size_t)(n0 + r) * K + k0 + g * 8),
            (__attribute__((address_space(3))) void*)&Bs[(i * 256 + wave * 64) * 8], 16, 0, 0);
      }
    }
    __syncthreads();

    bf16x8 af[4], bfr[4];
#pragma unroll
    for (int i = 0; i < 4; ++i) {
      const int r = wm + i * 16 + mr;
      const int col = (q + (r >> 1)) & 3;
      af[i] = *(const bf16x8*)&As[r * 32 + col * 8];
    }
#pragma unroll
    for (int j = 0; j < 4; ++j) {
      const int r = wn + j * 16 + mr;
      const int col = (q + (r >> 1)) & 3;
      bfr[j] = *(const bf16x8*)&Bs[r * 32 + col * 8];
    }
#pragma unroll
    for (int i = 0; i < 4; ++i)
#pragma unroll
      for (int j = 0; j < 4; ++j)
        acc[i][j] = __builtin_amdgcn_mfma_f32_16x16x32_bf16(af[i], bfr[j], acc[i][j], 0, 0, 0);
    __syncthreads();
  }

  // ---- epilogue: C/D layout col=lane&15, row=(lane>>4)*4+reg ----
  const int orow = (lane >> 4) * 4;
  const int ocol = lane & 15;
#pragma unroll
  for (int j = 0; j < 4; ++j) {
    const int col = n0 + wn + j * 16 + ocol;
    const float bj = bias[col];
#pragma unroll
    for (int i = 0; i < 4; ++i) {
      const int rbase = m0 + wm + i * 16 + orow;
#pragma unroll
      for (int r = 0; r < 4; ++r) {
        float v = acc[i][j][r] + bj;
        if (ACT) {
          v = 1.0f / (1.0f + __expf(-v));
          ((u16*)Cv)[(size_t)(rbase + r) * Nc + col] = f2bf(v);
        } else {
          ((float*)Cv)[(size_t)(rbase + r) * Nc + col] = v;
        }
      }
    }
  }
}

// ---------------------------------------------------------------------------
// Covariance: partial[z][a,b] = sum_{n in chunk z} f(P[n,a])*f(Q[n,b]), f(h)=h(1-h).
// 128x128 tile / block, 256 threads, 8x8 per thread. Z=256 split-K ->
// 512 blocks = 2 blocks/CU (staging latency hiding). XCD chunked swizzle so
// blocks sharing P/Q row-ranges are L2-co-resident.
// ---------------------------------------------------------------------------
__global__ __launch_bounds__(256, 2) void covar128(const u16* __restrict__ P,
                                                   const u16* __restrict__ Q,
                                                   float* __restrict__ partial,
                                                   int Ap, int Bq, int chunk) {
  __shared__ float Ps[16][132];
  __shared__ float Qs[16][132];
  const int tid = threadIdx.x;

  // chunked XCD swizzle over the full 3D grid (all dims powers of two)
  const int gx = gridDim.x, gy = gridDim.y;
  const int nwg = gx * gy * gridDim.z;
  int id = (blockIdx.z * gy + blockIdx.y) * gx + blockIdx.x;
  id = (id & 7) * (nwg >> 3) + (id >> 3);
  const int lgx = __builtin_ctz(gx), lgy = __builtin_ctz(gy);
  const int bx = id & (gx - 1);
  const int by = (id >> lgx) & (gy - 1);
  const int bz = id >> (lgx + lgy);

  const int a0 = bx * 128;
  const int b0 = by * 128;
  const int nbase = bz * chunk;
  const int tx = tid & 15, ty = tid >> 4;     // 16x16 thread grid
  float acc[8][8] = {};

  for (int nn = 0; nn < chunk; nn += 16) {
    // ---- stage 16 rows x 128 cols of f(P), f(Q); ty is the staging row ----
    {
      const u16* pr = P + (size_t)(nbase + nn + ty) * Ap + a0;
      const ushort4 v0 = *(const ushort4*)(pr + tx * 4);
      const ushort4 v1 = *(const ushort4*)(pr + 64 + tx * 4);
      float4 f0, f1;
      f0.x = sigd(v0.x); f0.y = sigd(v0.y); f0.z = sigd(v0.z); f0.w = sigd(v0.w);
      f1.x = sigd(v1.x); f1.y = sigd(v1.y); f1.z = sigd(v1.z); f1.w = sigd(v1.w);
      *(float4*)&Ps[ty][tx * 4] = f0;
      *(float4*)&Ps[ty][64 + tx * 4] = f1;
    }
    {
      const u16* qr = Q + (size_t)(nbase + nn + ty) * Bq + b0;
      const ushort4 v0 = *(const ushort4*)(qr + tx * 4);
      const ushort4 v1 = *(const ushort4*)(qr + 64 + tx * 4);
      float4 f0, f1;
      f0.x = sigd(v0.x); f0.y = sigd(v0.y); f0.z = sigd(v0.z); f0.w = sigd(v0.w);
      f1.x = sigd(v1.x); f1.y = sigd(v1.y); f1.z = sigd(v1.z); f1.w = sigd(v1.w);
      *(float4*)&Qs[ty][tx * 4] = f0;
      *(float4*)&Qs[ty][64 + tx * 4] = f1;
    }
    __syncthreads();
#pragma unroll
    for (int kk = 0; kk < 16; ++kk) {
      float av[8], bv[8];
      *(float4*)&av[0] = *(const float4*)&Ps[kk][ty * 4];
      *(float4*)&av[4] = *(const float4*)&Ps[kk][64 + ty * 4];
      *(float4*)&bv[0] = *(const float4*)&Qs[kk][tx * 4];
      *(float4*)&bv[4] = *(const float4*)&Qs[kk][64 + tx * 4];
#pragma unroll
      for (int i = 0; i < 8; ++i)
#pragma unroll
        for (int j = 0; j < 8; ++j) acc[i][j] += av[i] * bv[j];
    }
    __syncthreads();
  }

  float* outp = partial + (size_t)bz * Ap * Bq;
#pragma unroll
  for (int i = 0; i < 8; ++i) {
    const int ar = (i < 4) ? (ty * 4 + i) : (64 + ty * 4 + (i - 4));
    float4 v0, v1;
    v0.x = acc[i][0]; v0.y = acc[i][1]; v0.z = acc[i][2]; v0.w = acc[i][3];
    v1.x = acc[i][4]; v1.y = acc[i][5]; v1.z = acc[i][6]; v1.w = acc[i][7];
    *(float4*)&outp[(size_t)(a0 + ar) * Bq + b0 + tx * 4] = v0;
    *(float4*)&outp[(size_t)(a0 + ar) * Bq + b0 + 64 + tx * 4] = v1;
  }
}

__global__ void reduce_partial(const float* __restrict__ partial, float* __restrict__ out,
                               int S, int Z) {
  const int i = blockIdx.x * 256 + threadIdx.x;
  float s = 0.f;
  for (int z = 0; z < Z; ++z) s += partial[(size_t)z * S + i];
  out[i] = s;
}

// ---------------------------------------------------------------------------
// z = h2e @ W2 + b2 ; theta(z) ; dzb = theta @ Ew + Eb.  One wave per row.
// ---------------------------------------------------------------------------
__global__ void enc_l3_sindy(const u16* __restrict__ h2, const float* __restrict__ W2,
                             const float* __restrict__ b2, const float* __restrict__ Ew,
                             const float* __restrict__ Eb, float* __restrict__ z_out,
                             float* __restrict__ dzb_out) {
  const int lane = threadIdx.x & 63;
  const int row = blockIdx.x * 4 + (threadIdx.x >> 6);
  const ushort2 h = *(const ushort2*)(h2 + (size_t)row * 128 + lane * 2);
  const float hx = bf2f(h.x), hy = bf2f(h.y);
  const int k = lane * 2;
  float s[3];
#pragma unroll
  for (int l = 0; l < 3; ++l)
    s[l] = hx * W2[k * 3 + l] + hy * W2[(k + 1) * 3 + l];
#pragma unroll
  for (int off = 32; off > 0; off >>= 1) {
    s[0] += __shfl_xor(s[0], off);
    s[1] += __shfl_xor(s[1], off);
    s[2] += __shfl_xor(s[2], off);
  }
  if (lane == 0) {
    const float z0 = s[0] + b2[0];
    const float z1 = s[1] + b2[1];
    const float z2 = s[2] + b2[2];
    z_out[row * 3 + 0] = z0;
    z_out[row * 3 + 1] = z1;
    z_out[row * 3 + 2] = z2;
    float th[22];
    th[0] = 1.f; th[1] = 1.f; th[2] = 1.f;
    th[3] = z0; th[4] = z1; th[5] = z2;
    th[6] = z0 * z0; th[7] = z0 * z1; th[8] = z0 * z2;
    th[9] = z1 * z1; th[10] = z1 * z2; th[11] = z2 * z2;
    th[12] = z0 * z0 * z0; th[13] = z0 * z0 * z1; th[14] = z0 * z0 * z2;
    th[15] = z0 * z1 * z1; th[16] = z0 * z1 * z2; th[17] = z0 * z2 * z2;
    th[18] = z1 * z1 * z1; th[19] = z1 * z1 * z2; th[20] = z1 * z2 * z2;
    th[21] = z2 * z2 * z2;
    float d0 = Eb[0], d1 = Eb[1], d2 = Eb[2];
#pragma unroll
    for (int c = 0; c < 22; ++c) {
      d0 += th[c] * Ew[c * 3 + 0];
      d1 += th[c] * Ew[c * 3 + 1];
      d2 += th[c] * Ew[c * 3 + 2];
    }
    dzb_out[row * 3 + 0] = d0;
    dzb_out[row * 3 + 1] = d1;
    dzb_out[row * 3 + 2] = d2;
  }
}

// ---------------------------------------------------------------------------
// Fused T1 + Je: T1[l,b] = (1/N) sum_a W2[a,l]*W1[b,a]*Ce[a,b]  (LDS)
//                Je[l,k] = sum_b T1[l,b]*W0[k,b]
// ---------------------------------------------------------------------------
__global__ void t1je_kernel(const float* __restrict__ Ce, const float* __restrict__ W2,
                            const float* __restrict__ W1, const float* __restrict__ W0,
                            float* __restrict__ Je) {
  __shared__ float T1s[768];
  const int t = threadIdx.x;
  {
    const int b = t & 255, l = t >> 8;
    float acc = 0.f;
    for (int a = 0; a < 128; ++a)
      acc += W2[a * 3 + l] * W1[b * 128 + a] * Ce[a * 256 + b];
    T1s[l * 256 + b] = acc * (1.0f / 65536.0f);
  }
  __syncthreads();
  for (int idx = t; idx < 1536; idx += 768) {
    const int l = idx >> 9, k = idx & 511;
    const float* t1r = &T1s[l * 256];
    float acc = 0.f;
    for (int b = 0; b < 256; ++b) acc += t1r[b] * W0[(size_t)k * 256 + b];
    Je[l * 512 + k] = acc;
  }
}

// ---------------------------------------------------------------------------
// Fused T2 + Jd: T2[a,l] = (1/N) sum_b Cd[a,b]*V1[b,a]*V0[l,b]  (LDS)
//                Jd[k,l] = sum_a V2[a,k]*T2[a,l]
// ---------------------------------------------------------------------------
__global__ void t2jd_kernel(const float* __restrict__ Cd, const float* __restrict__ V1,
                            const float* __restrict__ V0, const float* __restrict__ V2,
                            float* __restrict__ Jd) {
  __shared__ float T2s[768];
  const int t = threadIdx.x;
  {
    const int a = t & 255, l = t >> 8;
    float acc = 0.f;
    for (int b = 0; b < 128; ++b)
      acc += Cd[a * 128 + b] * V1[b * 256 + a] * V0[l * 128 + b];
    T2s[a * 3 + l] = acc * (1.0f / 65536.0f);
  }
  __syncthreads();
  for (int idx = t; idx < 1536; idx += 768) {
    const int k = idx & 511, l = idx >> 9;
    float acc = 0.f;
    for (int a = 0; a < 256; ++a) acc += V2[(size_t)a * 512 + k] * T2s[a * 3 + l];
    Jd[k * 3 + l] = acc;
  }
}

// dz[n,l] = sum_k dx[n,k] * Je[l,k]
__global__ void dz_kernel(const float* __restrict__ dx, const float* __restrict__ Je,
                          float* __restrict__ dz) {
  __shared__ float sJe[1536];
  for (int i = threadIdx.x; i < 1536; i += 256) sJe[i] = Je[i];
  __syncthreads();
  const int lane = threadIdx.x & 63;
  const int row = blockIdx.x * 4 + (threadIdx.x >> 6);
  const int k = lane * 8;
  const float4 v0 = *(const float4*)(dx + (size_t)row * 512 + k);
  const float4 v1 = *(const float4*)(dx + (size_t)row * 512 + k + 4);
  float s[3];
#pragma unroll
  for (int l = 0; l < 3; ++l) {
    const float* j = sJe + l * 512 + k;
    s[l] = v0.x * j[0] + v0.y * j[1] + v0.z * j[2] + v0.w * j[3] +
           v1.x * j[4] + v1.y * j[5] + v1.z * j[6] + v1.w * j[7];
  }
#pragma unroll
  for (int off = 32; off > 0; off >>= 1) {
    s[0] += __shfl_xor(s[0], off);
    s[1] += __shfl_xor(s[1], off);
    s[2] += __shfl_xor(s[2], off);
  }
  if (lane == 0) {
    dz[row * 3 + 0] = s[0];
    dz[row * 3 + 1] = s[1];
    dz[row * 3 + 2] = s[2];
  }
}

// ---------------------------------------------------------------------------
// h1d[n,j] = sigmoid(sum_l z[n,l]*V0[l,j] + b0[j]) -> bf16
// ---------------------------------------------------------------------------
__global__ void dec_l1(const float* __restrict__ z, const float* __restrict__ V0,
                       const float* __restrict__ b0, u16* __restrict__ h1d) {
  const int t = threadIdx.x;
  const int j0 = (t & 15) * 8;
  const int n = blockIdx.x * 16 + (t >> 4);
  float w0[8], w1[8], w2[8], bb[8];
  *(float4*)&w0[0] = *(const float4*)(V0 + j0);
  *(float4*)&w0[4] = *(const float4*)(V0 + j0 + 4);
  *(float4*)&w1[0] = *(const float4*)(V0 + 128 + j0);
  *(float4*)&w1[4] = *(const float4*)(V0 + 128 + j0 + 4);
  *(float4*)&w2[0] = *(const float4*)(V0 + 256 + j0);
  *(float4*)&w2[4] = *(const float4*)(V0 + 256 + j0 + 4);
  *(float4*)&bb[0] = *(const float4*)(b0 + j0);
  *(float4*)&bb[4] = *(const float4*)(b0 + j0 + 4);
  const float z0 = z[n * 3 + 0], z1 = z[n * 3 + 1], z2 = z[n * 3 + 2];
  u16x8 o;
#pragma unroll
  for (int m = 0; m < 8; ++m) {
    const float v = z0 * w0[m] + z1 * w1[m] + z2 * w2[m] + bb[m];
    o[m] = f2bf(1.0f / (1.0f + __expf(-v)));
  }
  *(u16x8*)(h1d + (size_t)n * 128 + j0) = o;
}

// ---------------------------------------------------------------------------
// dxb[n,k] = sum_l dzb[n,l] * Jd[k,l]
// ---------------------------------------------------------------------------
__global__ void dxb_kernel(const float* __restrict__ dzb, const float* __restrict__ Jd,
                           float* __restrict__ dxb) {
  const int t = threadIdx.x;
  const int k0 = (t & 63) * 8;
  const int rbase = blockIdx.x * 16 + (t >> 6);
  float jf[24];                                    // Jd rows k0..k0+7 (3 each)
#pragma unroll
  for (int q = 0; q < 6; ++q)
    *(float4*)&jf[q * 4] = *(const float4*)(Jd + k0 * 3 + q * 4);
#pragma unroll
  for (int it = 0; it < 4; ++it) {
    const int n = rbase + it * 4;
    const float d0 = dzb[n * 3 + 0], d1 = dzb[n * 3 + 1], d2 = dzb[n * 3 + 2];
    float v[8];
#pragma unroll
    for (int m = 0; m < 8; ++m)
      v[m] = d0 * jf[m * 3 + 0] + d1 * jf[m * 3 + 1] + d2 * jf[m * 3 + 2];
    float* outp = dxb + (size_t)n * 512 + k0;
    *(float4*)&outp[0] = *(float4*)&v[0];
    *(float4*)&outp[4] = *(float4*)&v[4];
  }
}

extern "C" void kernel_launch(void* const* d_in, const int* in_sizes, int n_in,
                              void* d_out, int out_size, void* d_ws, size_t ws_size,
                              hipStream_t stream) {
  const int N = NROWS;
  const float* x   = (const float*)d_in[0];
  const float* dx  = (const float*)d_in[1];
  const float* eW0 = (const float*)d_in[3];
  const float* eb0 = (const float*)d_in[4];
  const float* eW1 = (const float*)d_in[5];
  const float* eb1 = (const float*)d_in[6];
  const float* eW2 = (const float*)d_in[7];
  const float* eb2 = (const float*)d_in[8];
  const float* dW0 = (const float*)d_in[9];
  const float* db0 = (const float*)d_in[10];
  const float* dW1 = (const float*)d_in[11];
  const float* db1 = (const float*)d_in[12];
  const float* dW2 = (const float*)d_in[13];
  const float* db2 = (const float*)d_in[14];
  const float* Ew  = (const float*)d_in[15];
  const float* Eb  = (const float*)d_in[16];

  float* out = (float*)d_out;
  float* z_out   = out;
  float* dz_out  = out + (size_t)N * 3;
  float* dzb_out = out + (size_t)N * 6;
  float* xb_out  = out + (size_t)N * 9;
  float* dxb_out = out + (size_t)N * 9 + (size_t)N * 512;

  // workspace layout (bf16 activations; decoder aliases encoder buffers)
  u16* h1e = (u16*)d_ws;                       // N*256 bf16
  u16* h2e = h1e + (size_t)N * 256;            // N*128 bf16
  u16* h2d = h1e;                              // alias (h1e dead after covarE)
  u16* h1d = h2e;                              // alias (h2e dead after covarE)
  u16* wbuf = h2e + (size_t)N * 128;
  u16* eW0t = wbuf;                            // 256*512
  u16* eW1t = eW0t + 131072;                   // 128*256
  u16* dW1t = eW1t + 32768;                    // 256*128
  u16* dW2t = dW1t + 32768;                    // 512*256
  float* partial = (float*)(dW2t + 131072);    // COVAR_Z * 32768 f32 (shared Ce/Cd)
  float* Ce = partial + (size_t)COVAR_Z * 32768;  // 128*256
  float* Cd = Ce + 32768;                      // 256*128
  float* Je = Cd + 32768;
  float* Jd = Je + 1536;

  prep_weights<<<1280, 256, 0, stream>>>(eW0, eW1, dW1, dW2, eW0t, eW1t, dW1t, dW2t);

  // encoder forward
  gemm_mfma<1, 1><<<dim3(2, N / 128), 256, 0, stream>>>(x, eW0t, eb0, h1e, 512, 256);
  gemm_mfma<1, 0><<<dim3(1, N / 128), 256, 0, stream>>>(h1e, eW1t, eb1, h2e, 256, 128);
  enc_l3_sindy<<<N / 4, 256, 0, stream>>>(h2e, eW2, eb2, Ew, Eb, z_out, dzb_out);

  // encoder mean-Jacobian
  covar128<<<dim3(1, 2, COVAR_Z), 256, 0, stream>>>(h2e, h1e, partial, 128, 256, N / COVAR_Z);
  reduce_partial<<<128, 256, 0, stream>>>(partial, Ce, 32768, COVAR_Z);
  t1je_kernel<<<1, 768, 0, stream>>>(Ce, eW2, eW1, eW0, Je);
  dz_kernel<<<N / 4, 256, 0, stream>>>(dx, Je, dz_out);

  // decoder forward (aliases: h1d<-h2e, h2d<-h1e; safe after covarE)
  dec_l1<<<N / 16, 256, 0, stream>>>(z_out, dW0, db0, h1d);
  gemm_mfma<1, 0><<<dim3(2, N / 128), 256, 0, stream>>>(h1d, dW1t, db1, h2d, 128, 256);
  gemm_mfma<0, 0><<<dim3(4, N / 128), 256, 0, stream>>>(h2d, dW2t, db2, xb_out, 256, 512);

  // decoder mean-Jacobian
  covar128<<<dim3(2, 1, COVAR_Z), 256, 0, stream>>>(h2d, h1d, partial, 256, 128, N / COVAR_Z);
  reduce_partial<<<128, 256, 0, stream>>>(partial, Cd, 32768, COVAR_Z);
  t2jd_kernel<<<1, 768, 0, stream>>>(Cd, dW1, dW0, dW2, Jd);
  dxb_kernel<<<N / 16, 256, 0, stream>>>(dzb_out, Jd, dxb_out);
}

// Round 5
// 942.597 us; speedup vs baseline: 1.0298x; 1.0298x over previous
//
#include <hip/hip_runtime.h>

#define NROWS 65536
#define COVAR_Z 256

typedef unsigned short u16;
typedef short bf16x8 __attribute__((ext_vector_type(8)));    // 8 bf16 in 4 VGPRs (MFMA operand)
typedef u16 u16x8 __attribute__((ext_vector_type(8)));
typedef u16 u16x4 __attribute__((ext_vector_type(4)));
typedef float f32x4 __attribute__((ext_vector_type(4)));

__device__ __forceinline__ u16 f2bf(float f) {
  unsigned int u = __builtin_bit_cast(unsigned int, f);
  u += 0x7FFFu + ((u >> 16) & 1u);   // round-to-nearest-even
  return (u16)(u >> 16);
}
__device__ __forceinline__ float bf2f(u16 s) {
  return __builtin_bit_cast(float, (unsigned int)s << 16);
}

// ---------------------------------------------------------------------------
// Weight prep: bf16 + transpose -> Wt[Nc][K] so B staging is k-contiguous.
// ---------------------------------------------------------------------------
__global__ void prep_weights(const float* __restrict__ eW0, const float* __restrict__ eW1,
                             const float* __restrict__ dW1, const float* __restrict__ dW2,
                             u16* __restrict__ eW0t, u16* __restrict__ eW1t,
                             u16* __restrict__ dW1t, u16* __restrict__ dW2t) {
  const int idx = blockIdx.x * 256 + threadIdx.x;
  if (idx < 131072) {                       // eW0 [512][256] -> eW0t[256][512]
    const int n = idx >> 9, k = idx & 511;
    eW0t[idx] = f2bf(eW0[k * 256 + n]);
  } else if (idx < 163840) {                // eW1 [256][128] -> eW1t[128][256]
    const int j = idx - 131072, n = j >> 8, k = j & 255;
    eW1t[j] = f2bf(eW1[k * 128 + n]);
  } else if (idx < 196608) {                // dW1 [128][256] -> dW1t[256][128]
    const int j = idx - 163840, n = j >> 7, k = j & 127;
    dW1t[j] = f2bf(dW1[k * 256 + n]);
  } else {                                  // dW2 [256][512] -> dW2t[512][256]
    const int j = idx - 196608, n = j >> 8, k = j & 255;
    dW2t[j] = f2bf(dW2[k * 512 + n]);
  }
}

// ---------------------------------------------------------------------------
// MFMA GEMM: C[M,Nc] = act(A[M,K] @ W[K,Nc] + bias).
// FT: also emit f-transposed buffer Ft[col][n] = bf16(p*(1-p)), p = bf16(sigmoid),
// so the mean-Jacobian covariances become MFMA GEMMs over K=n.
// ---------------------------------------------------------------------------
template <int ACT, int A_F32, int FT>
__global__ __launch_bounds__(256, 2) void gemm_mfma(const void* __restrict__ Av,
                                                    const u16* __restrict__ Wt,
                                                    const float* __restrict__ bias,
                                                    void* __restrict__ Cv,
                                                    u16* __restrict__ Ft,
                                                    int K, int Nc) {
  __shared__ u16 As[128 * 32];
  __shared__ u16 Bs[128 * 32];
  const int tid = threadIdx.x;
  const int lane = tid & 63;
  const int wave = tid >> 6;

  // chunked XCD swizzle (gridDim.x is a power of two: 1/2/4; nwg % 8 == 0)
  const int gx = gridDim.x;
  const int nwg = gx * gridDim.y;
  int id = blockIdx.y * gx + blockIdx.x;
  id = (id & 7) * (nwg >> 3) + (id >> 3);
  const int lgx = __builtin_ctz(gx);
  const int n0 = (id & (gx - 1)) * 128;
  const int m0 = (id >> lgx) * 128;

  const int wm = (wave & 1) * 64;
  const int wn = (wave >> 1) * 64;
  const int q = lane >> 4;       // k-group 0..3
  const int mr = lane & 15;

  f32x4 acc[4][4] = {};

  for (int k0 = 0; k0 < K; k0 += 32) {
    // ---- stage A tile [128 rows][32 k] ----
    if (A_F32) {
      const float* A = (const float*)Av;
#pragma unroll
      for (int i = 0; i < 2; ++i) {
        const int c = tid + i * 256;           // 16B chunk id
        const int r = c >> 2, p = c & 3;
        const int g = (p - (r >> 1)) & 3;      // swizzled global k-chunk
        const float* src = A + (size_t)(m0 + r) * K + k0 + g * 8;
        const float4 v0 = *(const float4*)src;
        const float4 v1 = *(const float4*)(src + 4);
        u16x8 w;
        w[0] = f2bf(v0.x); w[1] = f2bf(v0.y); w[2] = f2bf(v0.z); w[3] = f2bf(v0.w);
        w[4] = f2bf(v1.x); w[5] = f2bf(v1.y); w[6] = f2bf(v1.z); w[7] = f2bf(v1.w);
        *(u16x8*)&As[c * 8] = w;
      }
    } else {
      const u16* A = (const u16*)Av;
#pragma unroll
      for (int i = 0; i < 2; ++i) {
        const int c = tid + i * 256;
        const int r = c >> 2, p = c & 3;
        const int g = (p - (r >> 1)) & 3;
        __builtin_amdgcn_global_load_lds(
            (const __attribute__((address_space(1))) void*)(A + (size_t)(m0 + r) * K + k0 + g * 8),
            (__attribute__((address_space(3))) void*)&As[(i * 256 + wave * 64) * 8], 16, 0, 0);
      }
    }
    // ---- stage B tile: Wt rows n0..n0+127, k chunk ----
    {
#pragma unroll
      for (int i = 0; i < 2; ++i) {
        const int c = tid + i * 256;
        const int r = c >> 2, p = c & 3;
        const int g = (p - (r >> 1)) & 3;
        __builtin_amdgcn_global_load_lds(
            (const __attribute__((address_space(1))) void*)(Wt + (size_t)(n0 + r) * K + k0 + g * 8),
            (__attribute__((address_space(3))) void*)&Bs[(i * 256 + wave * 64) * 8], 16, 0, 0);
      }
    }
    __syncthreads();

    bf16x8 af[4], bfr[4];
#pragma unroll
    for (int i = 0; i < 4; ++i) {
      const int r = wm + i * 16 + mr;
      const int col = (q + (r >> 1)) & 3;
      af[i] = *(const bf16x8*)&As[r * 32 + col * 8];
    }
#pragma unroll
    for (int j = 0; j < 4; ++j) {
      const int r = wn + j * 16 + mr;
      const int col = (q + (r >> 1)) & 3;
      bfr[j] = *(const bf16x8*)&Bs[r * 32 + col * 8];
    }
#pragma unroll
    for (int i = 0; i < 4; ++i)
#pragma unroll
      for (int j = 0; j < 4; ++j)
        acc[i][j] = __builtin_amdgcn_mfma_f32_16x16x32_bf16(af[i], bfr[j], acc[i][j], 0, 0, 0);
    __syncthreads();
  }

  // ---- epilogue: C/D layout col=lane&15, row=(lane>>4)*4+reg ----
  const int orow = (lane >> 4) * 4;
  const int ocol = lane & 15;
#pragma unroll
  for (int j = 0; j < 4; ++j) {
    const int col = n0 + wn + j * 16 + ocol;
    const float bj = bias[col];
#pragma unroll
    for (int i = 0; i < 4; ++i) {
      const int rbase = m0 + wm + i * 16 + orow;
      u16 fr[4];
#pragma unroll
      for (int r = 0; r < 4; ++r) {
        float v = acc[i][j][r] + bj;
        if (ACT) {
          v = 1.0f / (1.0f + __expf(-v));
          const u16 sb = f2bf(v);
          ((u16*)Cv)[(size_t)(rbase + r) * Nc + col] = sb;
          if (FT) {
            const float p = bf2f(sb);
            fr[r] = f2bf(p * (1.0f - p));
          }
        } else {
          ((float*)Cv)[(size_t)(rbase + r) * Nc + col] = v;
        }
      }
      if (ACT && FT) {
        *(u16x4*)&Ft[(size_t)col * NROWS + rbase] = *(u16x4*)&fr[0];
      }
    }
  }
}

// ---------------------------------------------------------------------------
// Covariance as MFMA GEMM: partial[z][a,b] = sum_{n in chunk z} At[a,n]*Bt[b,n].
// At, Bt are the f-transposed bf16 buffers (stride NROWS, n-contiguous).
// Structure identical to gemm_mfma (both operands via the B staging path).
// grid = (Ncb/128, M/128, COVAR_Z); per-z output slab M*Ncb = 32768 f32.
// ---------------------------------------------------------------------------
__global__ __launch_bounds__(256, 2) void covar_gemm(const u16* __restrict__ At,
                                                     const u16* __restrict__ Bt,
                                                     float* __restrict__ partial,
                                                     int Ncb, int chunk) {
  __shared__ u16 As[128 * 32];
  __shared__ u16 Bs[128 * 32];
  const int tid = threadIdx.x;
  const int lane = tid & 63;
  const int wave = tid >> 6;

  // chunked XCD swizzle over the full 3D grid (all dims powers of two)
  const int gx = gridDim.x, gy = gridDim.y;
  const int nwg = gx * gy * gridDim.z;
  int id = (blockIdx.z * gy + blockIdx.y) * gx + blockIdx.x;
  id = (id & 7) * (nwg >> 3) + (id >> 3);
  const int lgx = __builtin_ctz(gx), lgy = __builtin_ctz(gy);
  const int bx = id & (gx - 1);
  const int by = (id >> lgx) & (gy - 1);
  const int bz = id >> (lgx + lgy);

  const int n0 = bx * 128;          // b-dim tile
  const int m0 = by * 128;          // a-dim tile
  const int kb = bz * chunk;        // n-range

  const int wm = (wave & 1) * 64;
  const int wn = (wave >> 1) * 64;
  const int q = lane >> 4;
  const int mr = lane & 15;

  f32x4 acc[4][4] = {};

  for (int k0 = kb; k0 < kb + chunk; k0 += 32) {
#pragma unroll
    for (int i = 0; i < 2; ++i) {
      const int c = tid + i * 256;
      const int r = c >> 2, p = c & 3;
      const int g = (p - (r >> 1)) & 3;
      __builtin_amdgcn_global_load_lds(
          (const __attribute__((address_space(1))) void*)(At + (size_t)(m0 + r) * NROWS + k0 + g * 8),
          (__attribute__((address_space(3))) void*)&As[(i * 256 + wave * 64) * 8], 16, 0, 0);
    }
#pragma unroll
    for (int i = 0; i < 2; ++i) {
      const int c = tid + i * 256;
      const int r = c >> 2, p = c & 3;
      const int g = (p - (r >> 1)) & 3;
      __builtin_amdgcn_global_load_lds(
          (const __attribute__((address_space(1))) void*)(Bt + (size_t)(n0 + r) * NROWS + k0 + g * 8),
          (__attribute__((address_space(3))) void*)&Bs[(i * 256 + wave * 64) * 8], 16, 0, 0);
    }
    __syncthreads();

    bf16x8 af[4], bfr[4];
#pragma unroll
    for (int i = 0; i < 4; ++i) {
      const int r = wm + i * 16 + mr;
      const int col = (q + (r >> 1)) & 3;
      af[i] = *(const bf16x8*)&As[r * 32 + col * 8];
    }
#pragma unroll
    for (int j = 0; j < 4; ++j) {
      const int r = wn + j * 16 + mr;
      const int col = (q + (r >> 1)) & 3;
      bfr[j] = *(const bf16x8*)&Bs[r * 32 + col * 8];
    }
#pragma unroll
    for (int i = 0; i < 4; ++i)
#pragma unroll
      for (int j = 0; j < 4; ++j)
        acc[i][j] = __builtin_amdgcn_mfma_f32_16x16x32_bf16(af[i], bfr[j], acc[i][j], 0, 0, 0);
    __syncthreads();
  }

  float* outp = partial + (size_t)bz * 32768;
  const int orow = (lane >> 4) * 4;
  const int ocol = lane & 15;
#pragma unroll
  for (int j = 0; j < 4; ++j) {
    const int col = n0 + wn + j * 16 + ocol;
#pragma unroll
    for (int i = 0; i < 4; ++i) {
      const int rbase = m0 + wm + i * 16 + orow;
#pragma unroll
      for (int r = 0; r < 4; ++r)
        outp[(size_t)(rbase + r) * Ncb + col] = acc[i][j][r];
    }
  }
}

__global__ void reduce_partial(const float* __restrict__ partial, float* __restrict__ out,
                               int S, int Z) {
  const int i = blockIdx.x * 256 + threadIdx.x;
  float s = 0.f;
  for (int z = 0; z < Z; ++z) s += partial[(size_t)z * S + i];
  out[i] = s;
}

// ---------------------------------------------------------------------------
// z = h2e @ W2 + b2 ; theta(z) ; dzb = theta @ Ew + Eb.  One wave per row.
// ---------------------------------------------------------------------------
__global__ void enc_l3_sindy(const u16* __restrict__ h2, const float* __restrict__ W2,
                             const float* __restrict__ b2, const float* __restrict__ Ew,
                             const float* __restrict__ Eb, float* __restrict__ z_out,
                             float* __restrict__ dzb_out) {
  const int lane = threadIdx.x & 63;
  const int row = blockIdx.x * 4 + (threadIdx.x >> 6);
  const ushort2 h = *(const ushort2*)(h2 + (size_t)row * 128 + lane * 2);
  const float hx = bf2f(h.x), hy = bf2f(h.y);
  const int k = lane * 2;
  float s[3];
#pragma unroll
  for (int l = 0; l < 3; ++l)
    s[l] = hx * W2[k * 3 + l] + hy * W2[(k + 1) * 3 + l];
#pragma unroll
  for (int off = 32; off > 0; off >>= 1) {
    s[0] += __shfl_xor(s[0], off);
    s[1] += __shfl_xor(s[1], off);
    s[2] += __shfl_xor(s[2], off);
  }
  if (lane == 0) {
    const float z0 = s[0] + b2[0];
    const float z1 = s[1] + b2[1];
    const float z2 = s[2] + b2[2];
    z_out[row * 3 + 0] = z0;
    z_out[row * 3 + 1] = z1;
    z_out[row * 3 + 2] = z2;
    float th[22];
    th[0] = 1.f; th[1] = 1.f; th[2] = 1.f;
    th[3] = z0; th[4] = z1; th[5] = z2;
    th[6] = z0 * z0; th[7] = z0 * z1; th[8] = z0 * z2;
    th[9] = z1 * z1; th[10] = z1 * z2; th[11] = z2 * z2;
    th[12] = z0 * z0 * z0; th[13] = z0 * z0 * z1; th[14] = z0 * z0 * z2;
    th[15] = z0 * z1 * z1; th[16] = z0 * z1 * z2; th[17] = z0 * z2 * z2;
    th[18] = z1 * z1 * z1; th[19] = z1 * z1 * z2; th[20] = z1 * z2 * z2;
    th[21] = z2 * z2 * z2;
    float d0 = Eb[0], d1 = Eb[1], d2 = Eb[2];
#pragma unroll
    for (int c = 0; c < 22; ++c) {
      d0 += th[c] * Ew[c * 3 + 0];
      d1 += th[c] * Ew[c * 3 + 1];
      d2 += th[c] * Ew[c * 3 + 2];
    }
    dzb_out[row * 3 + 0] = d0;
    dzb_out[row * 3 + 1] = d1;
    dzb_out[row * 3 + 2] = d2;
  }
}

// ---------------------------------------------------------------------------
// Fused T1 + Je: T1[l,b] = (1/N) sum_a W2[a,l]*W1[b,a]*Ce[a,b]  (LDS)
//                Je[l,k] = sum_b T1[l,b]*W0[k,b]
// ---------------------------------------------------------------------------
__global__ void t1je_kernel(const float* __restrict__ Ce, const float* __restrict__ W2,
                            const float* __restrict__ W1, const float* __restrict__ W0,
                            float* __restrict__ Je) {
  __shared__ float T1s[768];
  const int t = threadIdx.x;
  {
    const int b = t & 255, l = t >> 8;
    float acc = 0.f;
    for (int a = 0; a < 128; ++a)
      acc += W2[a * 3 + l] * W1[b * 128 + a] * Ce[a * 256 + b];
    T1s[l * 256 + b] = acc * (1.0f / 65536.0f);
  }
  __syncthreads();
  for (int idx = t; idx < 1536; idx += 768) {
    const int l = idx >> 9, k = idx & 511;
    const float* t1r = &T1s[l * 256];
    float acc = 0.f;
    for (int b = 0; b < 256; ++b) acc += t1r[b] * W0[(size_t)k * 256 + b];
    Je[l * 512 + k] = acc;
  }
}

// ---------------------------------------------------------------------------
// Fused T2 + Jd: T2[a,l] = (1/N) sum_b Cd[a,b]*V1[b,a]*V0[l,b]  (LDS)
//                Jd[k,l] = sum_a V2[a,k]*T2[a,l]
// ---------------------------------------------------------------------------
__global__ void t2jd_kernel(const float* __restrict__ Cd, const float* __restrict__ V1,
                            const float* __restrict__ V0, const float* __restrict__ V2,
                            float* __restrict__ Jd) {
  __shared__ float T2s[768];
  const int t = threadIdx.x;
  {
    const int a = t & 255, l = t >> 8;
    float acc = 0.f;
    for (int b = 0; b < 128; ++b)
      acc += Cd[a * 128 + b] * V1[b * 256 + a] * V0[l * 128 + b];
    T2s[a * 3 + l] = acc * (1.0f / 65536.0f);
  }
  __syncthreads();
  for (int idx = t; idx < 1536; idx += 768) {
    const int k = idx & 511, l = idx >> 9;
    float acc = 0.f;
    for (int a = 0; a < 256; ++a) acc += V2[(size_t)a * 512 + k] * T2s[a * 3 + l];
    Jd[k * 3 + l] = acc;
  }
}

// dz[n,l] = sum_k dx[n,k] * Je[l,k]
__global__ void dz_kernel(const float* __restrict__ dx, const float* __restrict__ Je,
                          float* __restrict__ dz) {
  __shared__ float sJe[1536];
  for (int i = threadIdx.x; i < 1536; i += 256) sJe[i] = Je[i];
  __syncthreads();
  const int lane = threadIdx.x & 63;
  const int row = blockIdx.x * 4 + (threadIdx.x >> 6);
  const int k = lane * 8;
  const float4 v0 = *(const float4*)(dx + (size_t)row * 512 + k);
  const float4 v1 = *(const float4*)(dx + (size_t)row * 512 + k + 4);
  float s[3];
#pragma unroll
  for (int l = 0; l < 3; ++l) {
    const float* j = sJe + l * 512 + k;
    s[l] = v0.x * j[0] + v0.y * j[1] + v0.z * j[2] + v0.w * j[3] +
           v1.x * j[4] + v1.y * j[5] + v1.z * j[6] + v1.w * j[7];
  }
#pragma unroll
  for (int off = 32; off > 0; off >>= 1) {
    s[0] += __shfl_xor(s[0], off);
    s[1] += __shfl_xor(s[1], off);
    s[2] += __shfl_xor(s[2], off);
  }
  if (lane == 0) {
    dz[row * 3 + 0] = s[0];
    dz[row * 3 + 1] = s[1];
    dz[row * 3 + 2] = s[2];
  }
}

// ---------------------------------------------------------------------------
// h1d[n,j] = sigmoid(sum_l z[n,l]*V0[l,j] + b0[j]) -> bf16 row-major
// plus h1dT[j,n] = bf16(p*(1-p)) transposed (covar operand).
// j = t&127; each thread covers 16 n (32 B contiguous fT run).
// ---------------------------------------------------------------------------
__global__ void dec_l1(const float* __restrict__ z, const float* __restrict__ V0,
                       const float* __restrict__ b0, u16* __restrict__ h1d,
                       u16* __restrict__ h1dT) {
  const int t = threadIdx.x;
  const int j = t & 127;
  const int half = t >> 7;
  const int n0 = blockIdx.x * 32 + half * 16;
  const float w0 = V0[j], w1 = V0[128 + j], w2 = V0[256 + j], bb = b0[j];
  u16 fv[16];
#pragma unroll
  for (int s = 0; s < 16; ++s) {
    const int n = n0 + s;
    const float z0 = z[n * 3 + 0], z1 = z[n * 3 + 1], z2 = z[n * 3 + 2];
    const float v = 1.0f / (1.0f + __expf(-(z0 * w0 + z1 * w1 + z2 * w2 + bb)));
    const u16 sb = f2bf(v);
    h1d[(size_t)n * 128 + j] = sb;
    const float p = bf2f(sb);
    fv[s] = f2bf(p * (1.0f - p));
  }
  *(u16x8*)&h1dT[(size_t)j * NROWS + n0] = *(u16x8*)&fv[0];
  *(u16x8*)&h1dT[(size_t)j * NROWS + n0 + 8] = *(u16x8*)&fv[8];
}

// ---------------------------------------------------------------------------
// dxb[n,k] = sum_l dzb[n,l] * Jd[k,l]
// ---------------------------------------------------------------------------
__global__ void dxb_kernel(const float* __restrict__ dzb, const float* __restrict__ Jd,
                           float* __restrict__ dxb) {
  const int t = threadIdx.x;
  const int k0 = (t & 63) * 8;
  const int rbase = blockIdx.x * 16 + (t >> 6);
  float jf[24];                                    // Jd rows k0..k0+7 (3 each)
#pragma unroll
  for (int q = 0; q < 6; ++q)
    *(float4*)&jf[q * 4] = *(const float4*)(Jd + k0 * 3 + q * 4);
#pragma unroll
  for (int it = 0; it < 4; ++it) {
    const int n = rbase + it * 4;
    const float d0 = dzb[n * 3 + 0], d1 = dzb[n * 3 + 1], d2 = dzb[n * 3 + 2];
    float v[8];
#pragma unroll
    for (int m = 0; m < 8; ++m)
      v[m] = d0 * jf[m * 3 + 0] + d1 * jf[m * 3 + 1] + d2 * jf[m * 3 + 2];
    float* outp = dxb + (size_t)n * 512 + k0;
    *(float4*)&outp[0] = *(float4*)&v[0];
    *(float4*)&outp[4] = *(float4*)&v[4];
  }
}

extern "C" void kernel_launch(void* const* d_in, const int* in_sizes, int n_in,
                              void* d_out, int out_size, void* d_ws, size_t ws_size,
                              hipStream_t stream) {
  const int N = NROWS;
  const float* x   = (const float*)d_in[0];
  const float* dx  = (const float*)d_in[1];
  const float* eW0 = (const float*)d_in[3];
  const float* eb0 = (const float*)d_in[4];
  const float* eW1 = (const float*)d_in[5];
  const float* eb1 = (const float*)d_in[6];
  const float* eW2 = (const float*)d_in[7];
  const float* eb2 = (const float*)d_in[8];
  const float* dW0 = (const float*)d_in[9];
  const float* db0 = (const float*)d_in[10];
  const float* dW1 = (const float*)d_in[11];
  const float* db1 = (const float*)d_in[12];
  const float* dW2 = (const float*)d_in[13];
  const float* db2 = (const float*)d_in[14];
  const float* Ew  = (const float*)d_in[15];
  const float* Eb  = (const float*)d_in[16];

  float* out = (float*)d_out;
  float* z_out   = out;
  float* dz_out  = out + (size_t)N * 3;
  float* dzb_out = out + (size_t)N * 6;
  float* xb_out  = out + (size_t)N * 9;
  float* dxb_out = out + (size_t)N * 9 + (size_t)N * 512;

  // workspace layout (bf16 activations + f-transposed covar operands)
  u16* h1e  = (u16*)d_ws;                      // N*256
  u16* h2e  = h1e  + (size_t)N * 256;          // N*128
  u16* h1eT = h2e  + (size_t)N * 128;          // 256*N  f(h1e)^T
  u16* h2eT = h1eT + (size_t)N * 256;          // 128*N  f(h2e)^T
  u16* h1d  = h2eT + (size_t)N * 128;          // N*128
  u16* h1dT = h1d  + (size_t)N * 128;          // 128*N  f(h1d)^T
  u16* h2d  = h1dT + (size_t)N * 128;          // N*256
  u16* h2dT = h2d  + (size_t)N * 256;          // 256*N  f(h2d)^T
  u16* wbuf = h2dT + (size_t)N * 256;
  u16* eW0t = wbuf;                            // 256*512
  u16* eW1t = eW0t + 131072;                   // 128*256
  u16* dW1t = eW1t + 32768;                    // 256*128
  u16* dW2t = dW1t + 32768;                    // 512*256
  float* partial = (float*)(dW2t + 131072);    // COVAR_Z * 32768 f32 (shared Ce/Cd)
  float* Ce = partial + (size_t)COVAR_Z * 32768;  // 128*256
  float* Cd = Ce + 32768;                      // 256*128
  float* Je = Cd + 32768;
  float* Jd = Je + 1536;

  const int chunk = N / COVAR_Z;

  prep_weights<<<1280, 256, 0, stream>>>(eW0, eW1, dW1, dW2, eW0t, eW1t, dW1t, dW2t);

  // encoder forward (emit f-transposed operands for the covar GEMMs)
  gemm_mfma<1, 1, 1><<<dim3(2, N / 128), 256, 0, stream>>>(x, eW0t, eb0, h1e, h1eT, 512, 256);
  gemm_mfma<1, 0, 1><<<dim3(1, N / 128), 256, 0, stream>>>(h1e, eW1t, eb1, h2e, h2eT, 256, 128);
  enc_l3_sindy<<<N / 4, 256, 0, stream>>>(h2e, eW2, eb2, Ew, Eb, z_out, dzb_out);

  // encoder mean-Jacobian: Ce = f(h2e)^T @ f(h1e) via MFMA split-K
  covar_gemm<<<dim3(2, 1, COVAR_Z), 256, 0, stream>>>(h2eT, h1eT, partial, 256, chunk);
  reduce_partial<<<128, 256, 0, stream>>>(partial, Ce, 32768, COVAR_Z);
  t1je_kernel<<<1, 768, 0, stream>>>(Ce, eW2, eW1, eW0, Je);
  dz_kernel<<<N / 4, 256, 0, stream>>>(dx, Je, dz_out);

  // decoder forward
  dec_l1<<<N / 32, 256, 0, stream>>>(z_out, dW0, db0, h1d, h1dT);
  gemm_mfma<1, 0, 1><<<dim3(2, N / 128), 256, 0, stream>>>(h1d, dW1t, db1, h2d, h2dT, 128, 256);
  gemm_mfma<0, 0, 0><<<dim3(4, N / 128), 256, 0, stream>>>(h2d, dW2t, db2, xb_out, nullptr, 256, 512);

  // decoder mean-Jacobian: Cd = f(h2d)^T @ f(h1d) via MFMA split-K
  covar_gemm<<<dim3(1, 2, COVAR_Z), 256, 0, stream>>>(h2dT, h1dT, partial, 128, chunk);
  reduce_partial<<<128, 256, 0, stream>>>(partial, Cd, 32768, COVAR_Z);
  t2jd_kernel<<<1, 768, 0, stream>>>(Cd, dW1, dW0, dW2, Jd);
  dxb_kernel<<<N / 16, 256, 0, stream>>>(dzb_out, Jd, dxb_out);
}